// Round 2
// baseline (2800.576 us; speedup 1.0000x reference)
//
#include <hip/hip_runtime.h>
#include <cfloat>
#include <math.h>

#define NOBS   256
#define NY     50
#define NX     30
#define NITER  400
#define LRATE  0.05f
#define CSTR   260     // ep_t column stride (floats); %4==0 keeps float4 LDS loads 16B-aligned
#define THRANK 40      // theta tracks the rank-40 KEY -> C = 41 every valid iter (stable)

__device__ __forceinline__ float rl_f(float x, int k) {
  return __int_as_float(__builtin_amdgcn_readlane(__float_as_int(x), k));
}
__device__ __forceinline__ unsigned rl_u(unsigned x, int k) {
  return (unsigned)__builtin_amdgcn_readlane((int)x, k);
}

// wave64 max: row_shr 1,2,4,8 + row_bcast 15,31; old=x keeps unwritten lanes at identity.
#define DPP_MAXSTEP(x, ctrl)                                                       \
  x = fmaxf(x, __int_as_float(__builtin_amdgcn_update_dpp(                         \
        __float_as_int(x), __float_as_int(x), (ctrl), 0xF, 0xF, false)))

// R2: readlane-starved design. Theory: wall ~= 15cyc * instrs + 450 * barriers, driven by
// v_readlane->use hazards (~35% of instr mix before). This version:
//   fwd: z[50] replicated per-lane array -> 50 pure fma, 0 rl (was 50 rl)
//   proj: per-lane Michelot on register array -> 0 rl, 0 barriers (was 50 rl + barrier)
//   grad: LDS atomicAdd into parity-buffered s4[51], broadcast b128 readback (was rl + exchange)
//   keys: u32 (r bits; stable-sort tiebreak only matters on exact f32 ties) -> scan rl halved
// Remaining rl/iter ~77 (scan 44 + bwd 32) vs 151 (R0) / 246 (R1). 512 thr, 8 waves, 2 barriers.
__global__ __launch_bounds__(512)
void dro_kernel(
    const float* __restrict__ X, const float* __restrict__ Y,
    const float* __restrict__ W, const float* __restrict__ Bb,
    const float* __restrict__ DLT, const float* __restrict__ GMM,
    float* __restrict__ out)
{
  __shared__ __align__(16) float ep_t[51 * CSTR];   // init staging (dead after epb load)
  __shared__ __align__(16) unsigned rrk[NOBS];      // full u32 keys (fallback scan)
  __shared__ __align__(16) unsigned ckey[128];      // 4 segments of 32 candidate slots
  __shared__ __align__(16) float s4buf[2][64];      // parity-buffered grad sums (51 used)
  __shared__ __align__(16) float yhs[64];           // y_hat row t (50 used)
  __shared__ __align__(16) float wmax4[4];
  __shared__ __align__(16) int   ccnt4[4];
  __shared__ __align__(16) int   wtie4[4];
  __shared__ unsigned th_key;

  const int tid  = threadIdx.x;     // 0..511
  const int oid  = tid & 255;       // owned observation
  const int half = tid >> 8;        // 0 = A, 1 = B (bwd obs-slice split; A writes LDS)
  const int lane = tid & 63;
  const int w8   = tid >> 6;        // wave 0..7
  const int wsc  = w8 & 3;          // obs quarter (obs base wsc*64)
  const int t    = blockIdx.x;      // scenario

  const float delta = DLT[0];
  const float gamma = GMM[0];
  const float a     = fminf(delta * 0.5f, 255.0f / 256.0f);
  const float a256  = a * 256.0f;

  // ---- init: FULL residual row of owned obs in registers; stage ep column-major (A only) ----
  float er[NY];
  {
    float xr[NX];
    #pragma unroll
    for (int k = 0; k < NX; ++k) xr[k] = X[oid * NX + k];
    #pragma unroll
    for (int j = 0; j < NY; ++j) {               // W/B wave-uniform -> scalar loads
      float acc = Bb[j];
      #pragma unroll
      for (int k = 0; k < NX; ++k) acc = fmaf(xr[k], W[j * NX + k], acc);
      er[j] = Y[oid * NY + j] - acc;
      if (half == 0) ep_t[j * CSTR + oid] = er[j];
    }
    if (half == 0) ep_t[NY * CSTR + oid] = 1.0f; // ones column -> c gradient
  }
  {                                              // y_hat row t: lane-parallel, to LDS + out
    const int jr = (tid < NY) ? tid : 0;
    float acc = Bb[jr];
    #pragma unroll
    for (int k = 0; k < NX; ++k) acc = fmaf(X[t * NX + k], W[jr * NX + k], acc);
    if (tid < NY) { out[NOBS * NY + t * NY + tid] = acc; yhs[tid] = acc; }
  }
  if (tid == 0) th_key = 0xFFFFFFFFu;            // iter 0: all candidates -> exact fallback
  if (tid < 128) ((float*)s4buf)[tid] = 0.0f;    // zero both parity buffers
  __syncthreads();

  // epb: iteration-invariant backward slice in registers. Lane l: col min(l,50),
  // obs [wsc*64 + half*32, +32). coef of obs wsc*64+half*32+q lives in lane half*32+q of
  // the SAME wave (both halves compute identical coef) -> bwd transpose is 32 in-wave rl.
  float epb[32];
  {
    const int colc = (lane < 51) ? lane : 50;
    const float* eb = &ep_t[colc * CSTR + wsc * 64 + half * 32];
    #pragma unroll
    for (int q = 0; q < 8; ++q) {
      const float4 e4 = *(const float4*)&eb[4 * q];
      epb[4*q+0] = e4.x; epb[4*q+1] = e4.y; epb[4*q+2] = e4.z; epb[4*q+3] = e4.w;
    }
  }

  float z[NY];                                   // z replicated per-lane (identical all threads)
  #pragma unroll
  for (int j = 0; j < NY; ++j) z[j] = 1.0f / NY;
  float cc = 0.0f;                               // c, replicated (bitwise identical)

  #pragma unroll 1
  for (int it = 0; it < NITER; ++it) {
    const int par = it & 1;
    const unsigned thk = th_key;                 // written pre-B2 prev iter -> fenced

    // ---- P0 (local): fwd dot from registers (0 rl); key; wave max+ties; compaction ----
    float d0 = 0.f, d1 = 0.f, d2 = 0.f, d3 = 0.f;
    #pragma unroll
    for (int j = 0; j < 48; j += 4) {
      d0 = fmaf(er[j + 0], z[j + 0], d0);
      d1 = fmaf(er[j + 1], z[j + 1], d1);
      d2 = fmaf(er[j + 2], z[j + 2], d2);
      d3 = fmaf(er[j + 3], z[j + 3], d3);
    }
    d0 = fmaf(er[48], z[48], d0);
    d1 = fmaf(er[49], z[49], d1);
    const float u = ((d0 + d2) + (d1 + d3)) - cc;
    const float r = u * u;
    const unsigned key = __float_as_uint(r);     // non-negative f32 bits sort as u32

    float m = r;
    DPP_MAXSTEP(m, 0x111); DPP_MAXSTEP(m, 0x112);
    DPP_MAXSTEP(m, 0x114); DPP_MAXSTEP(m, 0x118);
    DPP_MAXSTEP(m, 0x142); DPP_MAXSTEP(m, 0x143);
    const float mw = rl_f(m, 63);                // wave max
    const int   wt = __popcll(__ballot(r == mw));// ties vs wave max

    const bool cond = (key <= thk);
    const unsigned long long cmask = __ballot(cond);
    const unsigned long long lml   = (1ull << lane) - 1ull;
    const int cpos = __popcll(cmask & lml);
    const int cq   = __popcll(cmask);
    if (half == 0) {
      rrk[oid] = key;
      if (cond && cpos < 32) ckey[wsc * 32 + cpos] = key;       // own 32-slot segment
      const int padc  = (0 - cq) & 3;                           // sentinel-pad to mult of 4
      const int ncpos = __popcll(~cmask & lml);
      if (!cond && ncpos < padc && (cq + ncpos) < 32) ckey[wsc * 32 + cq + ncpos] = 0xFFFFFFFFu;
      if (lane == 0) { wmax4[wsc] = mw; ccnt4[wsc] = cq; wtie4[wsc] = wt; }
    }
    __syncthreads();                             // B1: ckey + stats + rrk

    // ---- P1: global max/ties; exact rank via segmented candidate scan; backward ----
    const float4 wm  = *(const float4*)wmax4;
    const int4   cn  = *(const int4*)ccnt4;
    const int4   wtv = *(const int4*)wtie4;
    const float mx = fmaxf(fmaxf(wm.x, wm.y), fmaxf(wm.z, wm.w));
    const int   cm = (wm.x == mx ? wtv.x : 0) + (wm.y == mx ? wtv.y : 0)
                   + (wm.z == mx ? wtv.z : 0) + (wm.w == mx ? wtv.w : 0);
    const bool ismax = (r == mx);

    const int c0u = __builtin_amdgcn_readfirstlane(cn.x);
    const int c1u = __builtin_amdgcn_readfirstlane(cn.y);
    const int c2u = __builtin_amdgcn_readfirstlane(cn.z);
    const int c3u = __builtin_amdgcn_readfirstlane(cn.w);
    const int C = (c0u + c1u) + (c2u + c3u);
    const bool valid = ((float)C >= a256) &&
        (c0u <= 32) && (c1u <= 32) && (c2u <= 32) && (c3u <= 32);

    int cnt;
    if (__builtin_expect(valid, 1)) {
      // candidates (keys<=thk) are downward-closed -> candidate rank == exact global rank;
      // non-candidates get cnt=C>=a256 -> gfac=1/256 exactly as required.
      const unsigned ck0 = ckey[lane];           // slots 0..63  (segments 0,1)
      const unsigned ck1 = ckey[64 + lane];      // slots 64..127 (segments 2,3)
      const int g0 = (c0u + 3) >> 2, g1 = (c1u + 3) >> 2;
      const int g2 = (c2u + 3) >> 2, g3 = (c3u + 3) >> 2;
      int n0 = 0, n1 = 0, n2 = 0, n3 = 0;
      #pragma unroll 1
      for (int s = 0; s < g0; ++s) {
        const int b = 4 * s;
        n0 += (rl_u(ck0, b + 0) < key) ? 1 : 0;
        n1 += (rl_u(ck0, b + 1) < key) ? 1 : 0;
        n2 += (rl_u(ck0, b + 2) < key) ? 1 : 0;
        n3 += (rl_u(ck0, b + 3) < key) ? 1 : 0;
      }
      #pragma unroll 1
      for (int s = 0; s < g1; ++s) {
        const int b = 32 + 4 * s;
        n0 += (rl_u(ck0, b + 0) < key) ? 1 : 0;
        n1 += (rl_u(ck0, b + 1) < key) ? 1 : 0;
        n2 += (rl_u(ck0, b + 2) < key) ? 1 : 0;
        n3 += (rl_u(ck0, b + 3) < key) ? 1 : 0;
      }
      #pragma unroll 1
      for (int s = 0; s < g2; ++s) {
        const int b = 4 * s;
        n0 += (rl_u(ck1, b + 0) < key) ? 1 : 0;
        n1 += (rl_u(ck1, b + 1) < key) ? 1 : 0;
        n2 += (rl_u(ck1, b + 2) < key) ? 1 : 0;
        n3 += (rl_u(ck1, b + 3) < key) ? 1 : 0;
      }
      #pragma unroll 1
      for (int s = 0; s < g3; ++s) {
        const int b = 32 + 4 * s;
        n0 += (rl_u(ck1, b + 0) < key) ? 1 : 0;
        n1 += (rl_u(ck1, b + 1) < key) ? 1 : 0;
        n2 += (rl_u(ck1, b + 2) < key) ? 1 : 0;
        n3 += (rl_u(ck1, b + 3) < key) ? 1 : 0;
      }
      cnt = (n0 + n1) + (n2 + n3);
    } else {                                     // iter 0 / drift: exact full scan
      const uint4* p = (const uint4*)rrk;
      int nf = 0;
      #pragma unroll 8
      for (int j = 0; j < 64; ++j) {
        const uint4 kk = p[j];
        nf += (kk.x < key) ? 1 : 0;
        nf += (kk.y < key) ? 1 : 0;
        nf += (kk.z < key) ? 1 : 0;
        nf += (kk.w < key) ? 1 : 0;
      }
      cnt = nf;
    }
    if (half == 0 && cnt == THRANK && (!valid || cond)) th_key = key;

    const float gfac  = fminf(fmaxf((float)cnt + 1.0f - a256, 0.0f), 1.0f) * (1.0f / 256.0f);
    const float g     = gfac + (ismax ? (a / (float)cm) : 0.0f);
    const float coefv = 2.0f * u * g;

    // backward: 32-obs slice from epb registers; coef via in-wave rl (transpose)
    const int lb = half * 32;
    float q0 = 0.f, q1 = 0.f, q2 = 0.f, q3 = 0.f;
    #pragma unroll
    for (int q = 0; q < 8; ++q) {
      q0 = fmaf(rl_f(coefv, lb + 4 * q + 0), epb[4 * q + 0], q0);
      q1 = fmaf(rl_f(coefv, lb + 4 * q + 1), epb[4 * q + 1], q1);
      q2 = fmaf(rl_f(coefv, lb + 4 * q + 2), epb[4 * q + 2], q2);
      q3 = fmaf(rl_f(coefv, lb + 4 * q + 3), epb[4 * q + 3], q3);
    }
    const float part = (q0 + q2) + (q1 + q3);
    if (lane <= 50) atomicAdd(&s4buf[par][lane], part);   // 8 contributions per dim
    __syncthreads();                             // B2: s4buf[par] + th_key

    // ---- P2 (local): z/c update + per-lane Michelot simplex projection (0 rl) ----
    const float* s4p = s4buf[par];
    const float lg = LRATE * gamma;
    #pragma unroll
    for (int jq = 0; jq < 12; ++jq) {            // v computed in place over z
      const float4 s4  = *(const float4*)&s4p[4 * jq];
      const float4 yh4 = *(const float4*)&yhs[4 * jq];
      z[4*jq+0] = fmaf(lg, yh4.x, fmaf(-LRATE, s4.x, z[4*jq+0]));
      z[4*jq+1] = fmaf(lg, yh4.y, fmaf(-LRATE, s4.y, z[4*jq+1]));
      z[4*jq+2] = fmaf(lg, yh4.z, fmaf(-LRATE, s4.z, z[4*jq+2]));
      z[4*jq+3] = fmaf(lg, yh4.w, fmaf(-LRATE, s4.w, z[4*jq+3]));
    }
    {
      const float4 s4 = *(const float4*)&s4p[48];
      z[48] = fmaf(lg, yhs[48], fmaf(-LRATE, s4.x, z[48]));
      z[49] = fmaf(lg, yhs[49], fmaf(-LRATE, s4.y, z[49]));
      cc = cc + LRATE * s4.z;                    // gc = -sum(coef); slot 50 = ones column
    }
    if (tid < 64) s4buf[par ^ 1][tid] = 0.0f;    // zero next parity buffer (fenced by next B1)

    // Michelot projection: same fixed point as reference's sort formula
    // (tau = (sum(support)-1)/rho); support shrinks monotonically; uniform branches
    // (all lanes hold identical data) -> no divergence.
    float tau = -FLT_MAX;
    int nprev = NY + 1;
    #pragma unroll 1
    for (int pass = 0; pass < 64; ++pass) {
      float s0 = -1.0f, s1 = 0.0f;
      int n = 0;
      #pragma unroll
      for (int j = 0; j < NY; j += 2) {
        const bool i0 = z[j]     > tau;
        const bool i1 = z[j + 1] > tau;
        s0 += i0 ? z[j]     : 0.0f;
        s1 += i1 ? z[j + 1] : 0.0f;
        n  += (i0 ? 1 : 0) + (i1 ? 1 : 0);
      }
      if (n == nprev) break;
      tau = (s0 + s1) / (float)n;
      nprev = n;
    }
    #pragma unroll
    for (int j = 0; j < NY; ++j) z[j] = fmaxf(z[j] - tau, 0.0f);
  }

  if (tid == 0) {
    #pragma unroll
    for (int j = 0; j < NY; ++j) out[t * NY + j] = z[j];
  }
}

extern "C" void kernel_launch(void* const* d_in, const int* in_sizes, int n_in,
                              void* d_out, int out_size, void* d_ws, size_t ws_size,
                              hipStream_t stream) {
  (void)in_sizes; (void)n_in; (void)d_ws; (void)ws_size; (void)out_size;
  const float* X   = (const float*)d_in[0];
  const float* Y   = (const float*)d_in[1];
  const float* W   = (const float*)d_in[2];
  const float* B   = (const float*)d_in[3];
  const float* DLT = (const float*)d_in[4];
  const float* GMM = (const float*)d_in[5];
  float* out = (float*)d_out;
  hipLaunchKernelGGL(dro_kernel, dim3(NOBS), dim3(512), 0, stream,
                     X, Y, W, B, DLT, GMM, out);
}

// Round 4
// 1134.137 us; speedup vs baseline: 2.4693x; 2.4693x over previous
//
#include <hip/hip_runtime.h>
#include <cfloat>
#include <math.h>

#define NOBS   256
#define NY     50
#define NX     30
#define NITER  400
#define LRATE  0.05f
#define CSTR   260     // ep_t column stride (floats); %4==0 keeps float4 LDS loads 16B-aligned
#define THRANK 40      // theta tracks the rank-40 KEY -> C = 41 every valid iter (stable)
#define CAND   48      // candidate capacity for the local scan (C<=48 -> valid fast path)

__device__ __forceinline__ float rl_f(float x, int k) {
  return __int_as_float(__builtin_amdgcn_readlane(__float_as_int(x), k));
}
__device__ __forceinline__ int rl_i(int x, int k) {
  return __builtin_amdgcn_readlane(x, k);
}

// wave64 max: row_shr 1,2,4,8 + row_bcast 15,31; old=x keeps unwritten lanes at identity.
#define DPP_MAXSTEP(x, ctrl)                                                       \
  x = fmaxf(x, __int_as_float(__builtin_amdgcn_update_dpp(                         \
        __float_as_int(x), __float_as_int(x), (ctrl), 0xF, 0xF, false)))

// R3 (resubmit; round-3 bench was a container-infra failure, no kernel signal):
// model from R0/R1/R2 fits T ~= 6ns*I_wave + 0.29us*B (lockstep replicated chains;
// waves don't hide each other's latency). Minimize BOTH terms: 3 barriers, I~440.
//  - dense atomic compaction (no prefix barrier), double-buffered ckey + sentinels
//  - rank scan = 12 broadcast b128 LDS loads + 96 local cmp/add (u32 keys, no rl, no exchange)
//  - cnt local -> th_key/coef/bwd in same phase
//  - projection scan split 8-way across waves (7 steps each), transposed-LDS combine
__global__ __launch_bounds__(512) __attribute__((amdgpu_waves_per_eu(2, 2)))
void dro_kernel(
    const float* __restrict__ X, const float* __restrict__ Y,
    const float* __restrict__ W, const float* __restrict__ Bb,
    const float* __restrict__ DLT, const float* __restrict__ GMM,
    float* __restrict__ out)
{
  __shared__ __align__(16) float ep_t[51 * CSTR];   // init staging (dead after epb load)
  __shared__ __align__(16) unsigned rrk[NOBS];      // full u32 keys (fallback scan)
  __shared__ __align__(16) unsigned ckey[2][128];   // parity-buffered dense candidates
  __shared__ __align__(16) float red8t[512];        // bwd partials, transposed [lane*8+w8]
  __shared__ __align__(16) float pjx[512];          // proj cs partials, [lane*8+w8]
  __shared__ __align__(16) float cjx[512];          // proj ahead partials, [lane*8+w8]
  __shared__ __align__(16) float wmax4[4];
  __shared__ __align__(16) int   wtie4[4];
  __shared__ int cctr[2];                           // parity-buffered candidate counter
  __shared__ unsigned th_key;

  const int tid  = threadIdx.x;     // 0..511
  const int oid  = tid & 255;       // owned observation
  const int half = tid >> 8;        // bwd obs-slice half; A(0) writes shared state
  const int lane = tid & 63;
  const int w8   = tid >> 6;        // wave 0..7
  const int wsc  = w8 & 3;          // obs quarter (obs base wsc*64)
  const int t    = blockIdx.x;      // scenario

  const float delta = DLT[0];
  const float gamma = GMM[0];
  const float a     = fminf(delta * 0.5f, 255.0f / 256.0f);
  const float a256  = a * 256.0f;

  // ---- init: FULL residual row of owned obs in registers; stage ep column-major (A) ----
  float er[NY];
  {
    float xr[NX];
    #pragma unroll
    for (int k = 0; k < NX; ++k) xr[k] = X[oid * NX + k];
    #pragma unroll
    for (int j = 0; j < NY; ++j) {               // W/B wave-uniform -> scalar loads
      float acc = Bb[j];
      #pragma unroll
      for (int k = 0; k < NX; ++k) acc = fmaf(xr[k], W[j * NX + k], acc);
      er[j] = Y[oid * NY + j] - acc;
      if (half == 0) ep_t[j * CSTR + oid] = er[j];
    }
    if (half == 0) ep_t[NY * CSTR + oid] = 1.0f; // ones column -> c gradient
  }
  float yhl;                                     // y_hat[t][lane] per-lane copy
  {
    const int jr = (lane < NY) ? lane : 0;
    float acc = Bb[jr];
    #pragma unroll
    for (int k = 0; k < NX; ++k) acc = fmaf(X[t * NX + k], W[jr * NX + k], acc);
    yhl = acc;
    if (tid < NY) out[NOBS * NY + t * NY + tid] = acc;
  }
  if (tid == 0) { th_key = 0xFFFFFFFFu; cctr[0] = 0; cctr[1] = 0; }
  if (tid < CAND) { ckey[0][tid] = 0xFFFFFFFFu; ckey[1][tid] = 0xFFFFFFFFu; }
  __syncthreads();

  // epb: iteration-invariant backward slice in registers. Lane l: col min(l,50),
  // obs [wsc*64 + half*32, +32). coef of those obs lives in lanes half*32+q of OWN wave.
  float epb[32];
  {
    const int colc = (lane < 51) ? lane : 50;
    const float* eb = &ep_t[colc * CSTR + wsc * 64 + half * 32];
    #pragma unroll
    for (int q = 0; q < 8; ++q) {
      const float4 e4 = *(const float4*)&eb[4 * q];
      epb[4*q+0] = e4.x; epb[4*q+1] = e4.y; epb[4*q+2] = e4.z; epb[4*q+3] = e4.w;
    }
  }

  float zv = (lane < NY) ? (1.0f / NY) : 0.0f;   // z one entry/lane, replicated per wave
  float cc = 0.0f;                               // c, replicated (bitwise identical)

  #pragma unroll 1
  for (int it = 0; it < NITER; ++it) {
    const int pp = it & 1;
    const unsigned thk = th_key;                 // last write 2 barriers ago -> fenced

    // ---- P0: full fwd dot (rl from own-wave zv); key; wave stats; atomic compaction ----
    float d0 = 0.f, d1 = 0.f, d2 = 0.f, d3 = 0.f;
    #pragma unroll
    for (int j = 0; j < 48; j += 4) {
      d0 = fmaf(er[j + 0], rl_f(zv, j + 0), d0);
      d1 = fmaf(er[j + 1], rl_f(zv, j + 1), d1);
      d2 = fmaf(er[j + 2], rl_f(zv, j + 2), d2);
      d3 = fmaf(er[j + 3], rl_f(zv, j + 3), d3);
    }
    d0 = fmaf(er[48], rl_f(zv, 48), d0);
    d1 = fmaf(er[49], rl_f(zv, 49), d1);
    const float u = ((d0 + d2) + (d1 + d3)) - cc;
    const float r = u * u;
    const unsigned key = __float_as_uint(r);     // non-negative f32 bits sort as u32

    float m = r;
    DPP_MAXSTEP(m, 0x111); DPP_MAXSTEP(m, 0x112);
    DPP_MAXSTEP(m, 0x114); DPP_MAXSTEP(m, 0x118);
    DPP_MAXSTEP(m, 0x142); DPP_MAXSTEP(m, 0x143);
    const float mw = rl_f(m, 63);                // wave (=quarter) max
    const int   wt = __popcll(__ballot(r == mw));

    const bool cond = (key <= thk);
    if (half == 0) {                             // A writes all shared state
      rrk[oid] = key;
      const unsigned long long cmask = __ballot(cond);
      const int cpos = __popcll(cmask & ((1ull << lane) - 1ull));
      const int cq   = __popcll(cmask);
      int base = 0;
      if (lane == 0) base = atomicAdd(&cctr[pp], cq);   // dense cross-quarter offset
      base = rl_i(base, 0);
      const int pos = base + cpos;               // slot order nondeterministic; cnt is
      if (cond && pos < 128) ckey[pp][pos] = key;//   order-independent -> deterministic
      if (lane == 0) { wmax4[wsc] = mw; wtie4[wsc] = wt; }
    }
    __syncthreads();                             // B1: ckey/cctr/stats/rrk

    // ---- P1: local rank scan (broadcast LDS loads); coef; bwd partials ----
    const int Cu = __builtin_amdgcn_readfirstlane(cctr[pp]);
    if (tid == 0) cctr[pp ^ 1] = 0;              // consumed last iter; next write 2 bar. away
    if (tid < CAND) ckey[pp ^ 1][tid] = 0xFFFFFFFFu;    // sentinel prefill for next iter

    const float4 wm  = *(const float4*)wmax4;
    const int4   wtv = *(const int4*)wtie4;
    const float mx = fmaxf(fmaxf(wm.x, wm.y), fmaxf(wm.z, wm.w));
    const int   cm = (wm.x == mx ? wtv.x : 0) + (wm.y == mx ? wtv.y : 0)
                   + (wm.z == mx ? wtv.z : 0) + (wm.w == mx ? wtv.w : 0);
    const bool ismax = (r == mx);
    const bool valid = ((float)Cu >= a256) && (Cu <= CAND);

    int cnt;
    if (__builtin_expect(valid, 1)) {
      // candidates (keys<=thk) downward-closed -> candidate rank == exact global rank;
      // non-candidates get cnt=C>=a256 -> gfac=1/256 (exact). Sentinels never count.
      const uint4* cp = (const uint4*)&ckey[pp][0];     // uniform addr -> broadcast reads
      int n0 = 0, n1 = 0, n2 = 0, n3 = 0;
      #pragma unroll
      for (int jq = 0; jq < CAND / 4; ++jq) {
        const uint4 k4 = cp[jq];
        n0 += (k4.x < key) ? 1 : 0;
        n1 += (k4.y < key) ? 1 : 0;
        n2 += (k4.z < key) ? 1 : 0;
        n3 += (k4.w < key) ? 1 : 0;
      }
      cnt = (n0 + n1) + (n2 + n3);
    } else {                                     // iter 0 / drift: exact full scan
      const uint4* p = (const uint4*)rrk;
      int n0 = 0, n1 = 0, n2 = 0, n3 = 0;
      #pragma unroll 4
      for (int jq = 0; jq < 64; ++jq) {
        const uint4 k4 = p[jq];
        n0 += (k4.x < key) ? 1 : 0;
        n1 += (k4.y < key) ? 1 : 0;
        n2 += (k4.z < key) ? 1 : 0;
        n3 += (k4.w < key) ? 1 : 0;
      }
      cnt = (n0 + n1) + (n2 + n3);
    }
    // rank-40 key refresh (unique when valid; A,B dup-write same value -> benign)
    if (cnt == THRANK && (!valid || cond)) th_key = key;

    const float gfac  = fminf(fmaxf((float)cnt + 1.0f - a256, 0.0f), 1.0f) * (1.0f / 256.0f);
    const float g     = gfac + (ismax ? (a / (float)cm) : 0.0f);
    const float coefv = 2.0f * u * g;

    // backward: 32-obs slice from epb regs; coef via in-wave rl (lanes lb..lb+31)
    const int lb = half * 32;
    float q0 = 0.f, q1 = 0.f, q2 = 0.f, q3 = 0.f;
    #pragma unroll
    for (int q = 0; q < 8; ++q) {
      q0 = fmaf(rl_f(coefv, lb + 4 * q + 0), epb[4 * q + 0], q0);
      q1 = fmaf(rl_f(coefv, lb + 4 * q + 1), epb[4 * q + 1], q1);
      q2 = fmaf(rl_f(coefv, lb + 4 * q + 2), epb[4 * q + 2], q2);
      q3 = fmaf(rl_f(coefv, lb + 4 * q + 3), epb[4 * q + 3], q3);
    }
    red8t[lane * 8 + w8] = (q0 + q2) + (q1 + q3);
    __syncthreads();                             // B2: red8t + th_key

    // ---- P2: z/c gradient step; 8-way wave-split projection scan ----
    const float4 ra = *(const float4*)&red8t[lane * 8];
    const float4 rb = *(const float4*)&red8t[lane * 8 + 4];
    const float s4 = ((ra.x + ra.y) + (ra.z + ra.w)) + ((rb.x + rb.y) + (rb.z + rb.w));
    cc = cc + LRATE * rl_f(s4, NY);              // gc = -sum(coef); lane 50 = ones column
    const float gz = s4 - gamma * yhl;
    const float v  = zv - LRATE * gz;            // identical across waves

    int ahp = 0; float cs = 0.0f;                // desc-sort scan, index tie-break (ref order)
    if (w8 < 7) {
      const int kb = 7 * w8;                     // waves 0..6: k in [7w, 7w+7)
      #pragma unroll
      for (int s = 0; s < 7; ++s) {
        const float vk = rl_f(v, kb + s);
        const bool b = (vk > v) || (vk == v && (kb + s) > lane);
        ahp += b ? 1 : 0;
        cs  += b ? vk : 0.0f;
      }
    } else {                                     // wave 7: k = 49 only
      const float vk = rl_f(v, 49);
      const bool b = (vk > v) || (vk == v && 49 > lane);
      ahp += b ? 1 : 0;
      cs  += b ? vk : 0.0f;
    }
    pjx[lane * 8 + w8] = cs;
    cjx[lane * 8 + w8] = (float)ahp;             // <=50, exact in f32
    __syncthreads();                             // B3: pjx/cjx

    // ---- P3: combine partials -> tau; z update (local, no further barrier) ----
    const float4 pa = *(const float4*)&pjx[lane * 8];
    const float4 pb = *(const float4*)&pjx[lane * 8 + 4];
    const float4 ca = *(const float4*)&cjx[lane * 8];
    const float4 cb = *(const float4*)&cjx[lane * 8 + 4];
    const float csF = ((pa.x + pa.y) + (pa.z + pa.w)) + ((pb.x + pb.y) + (pb.z + pb.w))
                    + v - 1.0f;
    const int aheadF = (int)(((ca.x + ca.y) + (ca.z + ca.w)) + ((cb.x + cb.y) + (cb.z + cb.w)));
    const bool pc = (lane < NY) && (v - csF / (float)(aheadF + 1) > 0.0f);
    const int rho = __popcll(__ballot(pc));      // >= 1 always
    const unsigned long long bsel = __ballot((lane < NY) && (aheadF == rho - 1));
    const int srcl = __ffsll(bsel) - 1;          // unique (ahp is a total order)
    const float tau =
        __int_as_float(__builtin_amdgcn_readlane(__float_as_int(csF), srcl)) / (float)rho;
    zv = (lane < NY) ? fmaxf(v - tau, 0.0f) : 0.0f;
  }

  if (w8 == 0 && lane < NY) out[t * NY + lane] = zv;

}

extern "C" void kernel_launch(void* const* d_in, const int* in_sizes, int n_in,
                              void* d_out, int out_size, void* d_ws, size_t ws_size,
                              hipStream_t stream) {
  (void)in_sizes; (void)n_in; (void)d_ws; (void)ws_size; (void)out_size;
  const float* X   = (const float*)d_in[0];
  const float* Y   = (const float*)d_in[1];
  const float* W   = (const float*)d_in[2];
  const float* B   = (const float*)d_in[3];
  const float* DLT = (const float*)d_in[4];
  const float* GMM = (const float*)d_in[5];
  float* out = (float*)d_out;
  hipLaunchKernelGGL(dro_kernel, dim3(NOBS), dim3(512), 0, stream,
                     X, Y, W, B, DLT, GMM, out);
}

// Round 5
// 1070.870 us; speedup vs baseline: 2.6152x; 1.0591x over previous
//
#include <hip/hip_runtime.h>
#include <cfloat>
#include <math.h>

#define NOBS   256
#define NY     50
#define NX     30
#define NITER  400
#define LRATE  0.05f
#define CSTR   260     // ep_t column stride (floats); %4==0 keeps float4 LDS loads 16B-aligned
#define THRANK 40      // theta tracks the rank-40 KEY -> C = 41 every valid iter (stable)
#define CAND   48      // candidate capacity for the local scan (C<=48 -> valid fast path)

__device__ __forceinline__ float rl_f(float x, int k) {
  return __int_as_float(__builtin_amdgcn_readlane(__float_as_int(x), k));
}
__device__ __forceinline__ int rl_i(int x, int k) {
  return __builtin_amdgcn_readlane(x, k);
}

// wave64 max: row_shr 1,2,4,8 + row_bcast 15,31; old=x keeps unwritten lanes at identity.
#define DPP_MAXSTEP(x, ctrl)                                                       \
  x = fmaxf(x, __int_as_float(__builtin_amdgcn_update_dpp(                         \
        __float_as_int(x), __float_as_int(x), (ctrl), 0xF, 0xF, false)))

// R5 (from R3=1134us): two levers under T ~= 6ns*I + 0.29us*B.
//  (1) conflict-free exchange layouts: [w8][lane] natural writes + 8 stride-64 scalar
//      combine reads (R3's [lane*8+w8] was a 16-way bank conflict: 5.4e7 cycles/dispatch).
//  (2) LDS-broadcast replaces readlane chains (the pattern that made R3's scan fast):
//      fwd dot reads z from a WAVE-PRIVATE LDS buffer (13 uniform b128, intra-wave,
//      no barrier); bwd coef transpose likewise (1 write + 8 uniform b128).
//  Overlays live in the dead-after-init ep_t buffer. Barriers stay at 3.
__global__ __launch_bounds__(512) __attribute__((amdgpu_waves_per_eu(2, 2)))
void dro_kernel(
    const float* __restrict__ X, const float* __restrict__ Y,
    const float* __restrict__ W, const float* __restrict__ Bb,
    const float* __restrict__ DLT, const float* __restrict__ GMM,
    float* __restrict__ out)
{
  __shared__ __align__(16) float smem[51 * CSTR];   // init: ep_t; after: overlays below
  __shared__ __align__(16) unsigned rrk[NOBS];      // full u32 keys (fallback scan)
  __shared__ __align__(16) unsigned ckey[2][128];   // parity-buffered dense candidates
  __shared__ __align__(16) float wmax4[4];
  __shared__ __align__(16) int   wtie4[4];
  __shared__ int cctr[2];                           // parity-buffered candidate counter
  __shared__ unsigned th_key;

  // Overlays (valid once ep_t is dead; all disjoint; zs/cfs are WAVE-PRIVATE):
  float*  const zs  = smem;                  // [8][64] replicated z per wave
  float*  const rdx = smem + 512;            // [8][64] bwd partials (cross-wave, B2)
  float*  const cfs = smem + 1024;           // [8][64] coef transpose (wave-private)
  float2* const pcx = (float2*)(smem + 1536);// [8][64] proj (cs, ahead) (cross-wave, B3)

  const int tid  = threadIdx.x;     // 0..511
  const int oid  = tid & 255;       // owned observation
  const int half = tid >> 8;        // bwd obs-slice half; A(0) writes shared state
  const int lane = tid & 63;
  const int w8   = tid >> 6;        // wave 0..7
  const int wsc  = w8 & 3;          // obs quarter (obs base wsc*64)
  const int t    = blockIdx.x;      // scenario

  const float delta = DLT[0];
  const float gamma = GMM[0];
  const float a     = fminf(delta * 0.5f, 255.0f / 256.0f);
  const float a256  = a * 256.0f;

  // ---- init: FULL residual row of owned obs in registers; stage ep column-major (A) ----
  float er[NY];
  {
    float xr[NX];
    #pragma unroll
    for (int k = 0; k < NX; ++k) xr[k] = X[oid * NX + k];
    #pragma unroll
    for (int j = 0; j < NY; ++j) {               // W/B wave-uniform -> scalar loads
      float acc = Bb[j];
      #pragma unroll
      for (int k = 0; k < NX; ++k) acc = fmaf(xr[k], W[j * NX + k], acc);
      er[j] = Y[oid * NY + j] - acc;
      if (half == 0) smem[j * CSTR + oid] = er[j];
    }
    if (half == 0) smem[NY * CSTR + oid] = 1.0f; // ones column -> c gradient
  }
  float yhl;                                     // y_hat[t][lane] per-lane copy
  {
    const int jr = (lane < NY) ? lane : 0;
    float acc = Bb[jr];
    #pragma unroll
    for (int k = 0; k < NX; ++k) acc = fmaf(X[t * NX + k], W[jr * NX + k], acc);
    yhl = acc;
    if (tid < NY) out[NOBS * NY + t * NY + tid] = acc;
  }
  if (tid == 0) { th_key = 0xFFFFFFFFu; cctr[0] = 0; cctr[1] = 0; }
  if (tid < CAND) { ckey[0][tid] = 0xFFFFFFFFu; ckey[1][tid] = 0xFFFFFFFFu; }
  __syncthreads();

  // epb: iteration-invariant backward slice in registers. Lane l: col min(l,50),
  // obs [wsc*64 + half*32, +32). coef of those obs -> cfs[w8*64 + half*32 + q].
  float epb[32];
  {
    const int colc = (lane < 51) ? lane : 50;
    const float* eb = &smem[colc * CSTR + wsc * 64 + half * 32];
    #pragma unroll
    for (int q = 0; q < 8; ++q) {
      const float4 e4 = *(const float4*)&eb[4 * q];
      epb[4*q+0] = e4.x; epb[4*q+1] = e4.y; epb[4*q+2] = e4.z; epb[4*q+3] = e4.w;
    }
  }
  __syncthreads();                               // ep_t dead -> overlays may be written

  float zv = (lane < NY) ? (1.0f / NY) : 0.0f;   // z one entry/lane, replicated per wave
  float cc = 0.0f;                               // c, replicated (bitwise identical)
  zs[w8 * 64 + lane] = zv;                       // wave-private z buffer (lanes>=50 -> 0)

  #pragma unroll 1
  for (int it = 0; it < NITER; ++it) {
    const int pp = it & 1;
    const unsigned thk = th_key;                 // last write 2 barriers ago -> fenced

    // ---- P0: fwd dot via wave-private LDS broadcast (13 b128, no rl chain) ----
    const float4* zp = (const float4*)&zs[w8 * 64];
    float d0 = 0.f, d1 = 0.f, d2 = 0.f, d3 = 0.f;
    #pragma unroll
    for (int jq = 0; jq < 12; ++jq) {
      const float4 z4 = zp[jq];
      d0 = fmaf(er[4*jq + 0], z4.x, d0);
      d1 = fmaf(er[4*jq + 1], z4.y, d1);
      d2 = fmaf(er[4*jq + 2], z4.z, d2);
      d3 = fmaf(er[4*jq + 3], z4.w, d3);
    }
    {
      const float4 z4 = zp[12];                  // z[48],z[49],0,0
      d0 = fmaf(er[48], z4.x, d0);
      d1 = fmaf(er[49], z4.y, d1);
    }
    const float u = ((d0 + d2) + (d1 + d3)) - cc;
    const float r = u * u;
    const unsigned key = __float_as_uint(r);     // non-negative f32 bits sort as u32

    float m = r;
    DPP_MAXSTEP(m, 0x111); DPP_MAXSTEP(m, 0x112);
    DPP_MAXSTEP(m, 0x114); DPP_MAXSTEP(m, 0x118);
    DPP_MAXSTEP(m, 0x142); DPP_MAXSTEP(m, 0x143);
    const float mw = rl_f(m, 63);                // wave (=quarter) max
    const int   wt = __popcll(__ballot(r == mw));

    const bool cond = (key <= thk);
    if (half == 0) {                             // A writes all shared state
      rrk[oid] = key;
      const unsigned long long cmask = __ballot(cond);
      const int cpos = __popcll(cmask & ((1ull << lane) - 1ull));
      const int cq   = __popcll(cmask);
      int base = 0;
      if (lane == 0) base = atomicAdd(&cctr[pp], cq);   // dense cross-quarter offset
      base = rl_i(base, 0);
      const int pos = base + cpos;               // slot order nondeterministic; cnt is
      if (cond && pos < 128) ckey[pp][pos] = key;//   order-independent -> deterministic
      if (lane == 0) { wmax4[wsc] = mw; wtie4[wsc] = wt; }
    }
    __syncthreads();                             // B1: ckey/cctr/stats/rrk

    // ---- P1: local rank scan (broadcast LDS loads); coef; bwd partials ----
    const int Cu = __builtin_amdgcn_readfirstlane(cctr[pp]);
    if (tid == 0) cctr[pp ^ 1] = 0;              // consumed last iter; next write 2 bar. away
    if (tid < CAND) ckey[pp ^ 1][tid] = 0xFFFFFFFFu;    // sentinel prefill for next iter

    const float4 wm  = *(const float4*)wmax4;
    const int4   wtv = *(const int4*)wtie4;
    const float mx = fmaxf(fmaxf(wm.x, wm.y), fmaxf(wm.z, wm.w));
    const int   cm = (wm.x == mx ? wtv.x : 0) + (wm.y == mx ? wtv.y : 0)
                   + (wm.z == mx ? wtv.z : 0) + (wm.w == mx ? wtv.w : 0);
    const bool ismax = (r == mx);
    const bool valid = ((float)Cu >= a256) && (Cu <= CAND);

    int cnt;
    if (__builtin_expect(valid, 1)) {
      // candidates (keys<=thk) downward-closed -> candidate rank == exact global rank;
      // non-candidates get cnt=C>=a256 -> gfac=1/256 (exact). Sentinels never count.
      const uint4* cp = (const uint4*)&ckey[pp][0];     // uniform addr -> broadcast reads
      int n0 = 0, n1 = 0, n2 = 0, n3 = 0;
      #pragma unroll
      for (int jq = 0; jq < CAND / 4; ++jq) {
        const uint4 k4 = cp[jq];
        n0 += (k4.x < key) ? 1 : 0;
        n1 += (k4.y < key) ? 1 : 0;
        n2 += (k4.z < key) ? 1 : 0;
        n3 += (k4.w < key) ? 1 : 0;
      }
      cnt = (n0 + n1) + (n2 + n3);
    } else {                                     // iter 0 / drift: exact full scan
      const uint4* p = (const uint4*)rrk;
      int n0 = 0, n1 = 0, n2 = 0, n3 = 0;
      #pragma unroll 4
      for (int jq = 0; jq < 64; ++jq) {
        const uint4 k4 = p[jq];
        n0 += (k4.x < key) ? 1 : 0;
        n1 += (k4.y < key) ? 1 : 0;
        n2 += (k4.z < key) ? 1 : 0;
        n3 += (k4.w < key) ? 1 : 0;
      }
      cnt = (n0 + n1) + (n2 + n3);
    }
    // rank-40 key refresh (unique when valid; A,B dup-write same value -> benign)
    if (cnt == THRANK && (!valid || cond)) th_key = key;

    const float gfac  = fminf(fmaxf((float)cnt + 1.0f - a256, 0.0f), 1.0f) * (1.0f / 256.0f);
    const float g     = gfac + (ismax ? (a / (float)cm) : 0.0f);
    const float coefv = 2.0f * u * g;

    // backward: coef transpose via wave-private LDS (1 write + 8 broadcast b128)
    cfs[w8 * 64 + lane] = coefv;                 // in-order DS: reads below see this
    const float4* cfp = (const float4*)&cfs[w8 * 64 + half * 32];
    float q0 = 0.f, q1 = 0.f, q2 = 0.f, q3 = 0.f;
    #pragma unroll
    for (int q = 0; q < 8; ++q) {
      const float4 c4 = cfp[q];                  // coef of obs wsc*64 + half*32 + 4q..+3
      q0 = fmaf(c4.x, epb[4 * q + 0], q0);
      q1 = fmaf(c4.y, epb[4 * q + 1], q1);
      q2 = fmaf(c4.z, epb[4 * q + 2], q2);
      q3 = fmaf(c4.w, epb[4 * q + 3], q3);
    }
    rdx[w8 * 64 + lane] = (q0 + q2) + (q1 + q3); // natural layout: conflict-free
    __syncthreads();                             // B2: rdx + th_key

    // ---- P2: z/c gradient step; 8-way wave-split projection scan ----
    const float r0 = rdx[lane],       r1 = rdx[64 + lane];
    const float r2 = rdx[128 + lane], r3 = rdx[192 + lane];
    const float r4 = rdx[256 + lane], r5 = rdx[320 + lane];
    const float r6 = rdx[384 + lane], r7 = rdx[448 + lane];
    const float s4 = ((r0 + r1) + (r2 + r3)) + ((r4 + r5) + (r6 + r7));
    cc = cc + LRATE * rl_f(s4, NY);              // gc = -sum(coef); lane 50 = ones column
    const float gz = s4 - gamma * yhl;
    const float v  = zv - LRATE * gz;            // identical across waves

    int ahp = 0; float cs = 0.0f;                // desc-sort scan, index tie-break (ref order)
    if (w8 < 7) {
      const int kb = 7 * w8;                     // waves 0..6: k in [7w, 7w+7)
      #pragma unroll
      for (int s = 0; s < 7; ++s) {
        const float vk = rl_f(v, kb + s);
        const bool b = (vk > v) || (vk == v && (kb + s) > lane);
        ahp += b ? 1 : 0;
        cs  += b ? vk : 0.0f;
      }
    } else {                                     // wave 7: k = 49 only
      const float vk = rl_f(v, 49);
      const bool b = (vk > v) || (vk == v && 49 > lane);
      ahp += b ? 1 : 0;
      cs  += b ? vk : 0.0f;
    }
    pcx[w8 * 64 + lane] = make_float2(cs, (float)ahp);  // stride-2: 2-way conflict = free
    __syncthreads();                             // B3: pcx

    // ---- P3: combine partials -> tau; z update; publish z to wave-private buffer ----
    const float2 p0 = pcx[lane],       p1 = pcx[64 + lane];
    const float2 p2 = pcx[128 + lane], p3 = pcx[192 + lane];
    const float2 p4 = pcx[256 + lane], p5 = pcx[320 + lane];
    const float2 p6 = pcx[384 + lane], p7 = pcx[448 + lane];
    const float csF = ((p0.x + p1.x) + (p2.x + p3.x)) + ((p4.x + p5.x) + (p6.x + p7.x))
                    + v - 1.0f;
    const int aheadF = (int)(((p0.y + p1.y) + (p2.y + p3.y))
                           + ((p4.y + p5.y) + (p6.y + p7.y)));
    const bool pc = (lane < NY) && (v - csF / (float)(aheadF + 1) > 0.0f);
    const int rho = __popcll(__ballot(pc));      // >= 1 always
    const unsigned long long bsel = __ballot((lane < NY) && (aheadF == rho - 1));
    const int srcl = __ffsll(bsel) - 1;          // unique (ahp is a total order)
    const float tau =
        __int_as_float(__builtin_amdgcn_readlane(__float_as_int(csF), srcl)) / (float)rho;
    zv = (lane < NY) ? fmaxf(v - tau, 0.0f) : 0.0f;
    zs[w8 * 64 + lane] = zv;                     // wave-private; next-iter P0 reads (in-order)
  }

  if (w8 == 0 && lane < NY) out[t * NY + lane] = zv;

}

extern "C" void kernel_launch(void* const* d_in, const int* in_sizes, int n_in,
                              void* d_out, int out_size, void* d_ws, size_t ws_size,
                              hipStream_t stream) {
  (void)in_sizes; (void)n_in; (void)d_ws; (void)ws_size; (void)out_size;
  const float* X   = (const float*)d_in[0];
  const float* Y   = (const float*)d_in[1];
  const float* W   = (const float*)d_in[2];
  const float* B   = (const float*)d_in[3];
  const float* DLT = (const float*)d_in[4];
  const float* GMM = (const float*)d_in[5];
  float* out = (float*)d_out;
  hipLaunchKernelGGL(dro_kernel, dim3(NOBS), dim3(512), 0, stream,
                     X, Y, W, B, DLT, GMM, out);
}